// Round 5
// baseline (207.366 us; speedup 1.0000x reference)
//
#include <hip/hip_runtime.h>
#include <cstdint>
#include <cstddef>

typedef __attribute__((ext_vector_type(8))) __bf16   bf16x8;
typedef __attribute__((ext_vector_type(2))) __bf16   bf16x2;
typedef __attribute__((ext_vector_type(4))) float    f32x4;
typedef __attribute__((ext_vector_type(4))) uint32_t u32x4;
typedef __attribute__((ext_vector_type(2))) uint32_t u32x2;

#define N_ROWS   1179648   // 8*384*384
#define N_TILES  73728     // N_ROWS/16
#define N_PAIRS  36864
#define BLOCKS   1024      // 4 waves -> 4096 waves -> 9 pairs/wave
#define PPW      9
#define SDIM     384
#define VOCAB    5

// tanh-form GELU via exp2+rcp on f32x4 (encourage v_pk_* codegen):
// gelu(x) ~= x / (1 + exp2(x*(c1 + c2*x^2))), |err| <= ~4e-4
__device__ __forceinline__ f32x4 gelu4(f32x4 x){
  f32x4 u = x * x;
  f32x4 w = u * (-0.10294456f) + (-2.3021255f);
  f32x4 z = x * w;
  f32x4 e;
  e[0] = __builtin_amdgcn_exp2f(z[0]);
  e[1] = __builtin_amdgcn_exp2f(z[1]);
  e[2] = __builtin_amdgcn_exp2f(z[2]);
  e[3] = __builtin_amdgcn_exp2f(z[3]);
  f32x4 d = e + 1.0f;
  f32x4 r;
  r[0] = __builtin_amdgcn_rcpf(d[0]);
  r[1] = __builtin_amdgcn_rcpf(d[1]);
  r[2] = __builtin_amdgcn_rcpf(d[2]);
  r[3] = __builtin_amdgcn_rcpf(d[3]);
  return x * r;
}

__device__ __forceinline__ bf16x8 mk_bf8(f32x4 a, f32x4 b){
  bf16x8 v;
  v[0]=(__bf16)a[0]; v[1]=(__bf16)a[1]; v[2]=(__bf16)a[2]; v[3]=(__bf16)a[3];
  v[4]=(__bf16)b[0]; v[5]=(__bf16)b[1]; v[6]=(__bf16)b[2]; v[7]=(__bf16)b[3];
  return v;
}

// LDS map: [0,24576) W1..W3 bf16 [m][k] swizzled; [24576,26624) Wo^T padded;
//          [26624,27392) b1|b2|b3 f32.  bounce: 4KB/wave (2 tiles x 2KB).
__global__ __launch_bounds__(256)
void mlp_kernel(const float* __restrict__ x,
                const float* __restrict__ W1, const float* __restrict__ b1,
                const float* __restrict__ W2, const float* __restrict__ b2,
                const float* __restrict__ W3, const float* __restrict__ b3,
                const float* __restrict__ lng, const float* __restrict__ lnb,
                const float* __restrict__ Wo,  const float* __restrict__ bo,
                float* __restrict__ tmp)
{
  __shared__ __align__(16) uint8_t  Wl[27392];
  __shared__ __align__(16) uint32_t bounce[4][1024];

  const int tid = threadIdx.x;

  // ---- stage weights: fp32 -> LDS bf16 [m][k], swizzle byte^=((m&7)<<4) ----
  {
    int m = tid & 63, g = tid >> 6;
    #pragma unroll 1
    for (int idx = g; idx < 96; idx += 4) {  // idx = L*32 + kp
      int L = idx >> 5, kp = idx & 31;
      const float* W = (L == 0) ? W1 : ((L == 1) ? W2 : W3);
      float lo = W[(2 * kp    ) * 64 + m];
      float hi = W[(2 * kp + 1) * 64 + m];
      bf16x2 p = { (__bf16)lo, (__bf16)hi };
      *(uint32_t*)(Wl + L * 8192 + m * 128 + ((4 * kp) ^ ((m & 7) << 4))) =
          __builtin_bit_cast(uint32_t, p);
    }
    int mm = tid & 15;
    #pragma unroll 1
    for (int kp = tid >> 4; kp < 32; kp += 16) {   // Wo^T rows 0..15
      float lo = (mm < VOCAB) ? Wo[(2 * kp    ) * VOCAB + mm] : 0.0f;
      float hi = (mm < VOCAB) ? Wo[(2 * kp + 1) * VOCAB + mm] : 0.0f;
      bf16x2 p = { (__bf16)lo, (__bf16)hi };
      *(uint32_t*)(Wl + 24576 + mm * 128 + ((4 * kp) ^ ((mm & 7) << 4))) =
          __builtin_bit_cast(uint32_t, p);
    }
    if (tid < 192) {
      float v = (tid < 64) ? b1[tid] : ((tid < 128) ? b2[tid - 64] : b3[tid - 128]);
      *(float*)(Wl + 26624 + tid * 4) = v;
    }
  }
  __syncthreads();

  const int wav  = tid >> 6, lane = tid & 63;
  const int h    = lane >> 4;
  const int b    = lane & 15;
  const int swzW = (b & 7) << 4;
  const int swzD = (b & 7) << 2;
  const int rowB = b * 128;
  const int kOff = 16 * h;
  uint32_t* myA = bounce[wav];          // tile A bounce (512 dwords)
  uint32_t* myBB = bounce[wav] + 512;   // tile B bounce
  float*    myF = (float*)bounce[wav];
  const float* biasL = (const float*)(Wl + 26624);

  f32x4 ggr[4], bbr[4], aoInit;
  #pragma unroll
  for (int mt = 0; mt < 4; ++mt) {
    ggr[mt] = *(const f32x4*)(lng + 16 * mt + 4 * h);
    bbr[mt] = *(const f32x4*)(lnb + 16 * mt + 4 * h);
  }
  #pragma unroll
  for (int r = 0; r < 4; ++r) {
    int v = 4 * h + r;
    aoInit[r] = (v < VOCAB) ? bo[v] : 0.0f;
  }

  const int gw = blockIdx.x * 4 + wav;   // 0..4095
  int t = gw * PPW * 2;                  // pair base tile (even)

  // prime prefetch of first pair (tiles t, t+1): 32 contiguous rows
  f32x4 xn[8];
  {
    const float* p0 = x + (size_t)(t * 16 + b) * 64 + 8 * h;
    xn[0] = *(const f32x4*)(p0);        xn[1] = *(const f32x4*)(p0 + 4);
    xn[2] = *(const f32x4*)(p0 + 32);   xn[3] = *(const f32x4*)(p0 + 36);
    const float* p1 = p0 + 1024;        // +16 rows
    xn[4] = *(const f32x4*)(p1);        xn[5] = *(const f32x4*)(p1 + 4);
    xn[6] = *(const f32x4*)(p1 + 32);   xn[7] = *(const f32x4*)(p1 + 36);
  }

  #pragma unroll 1
  for (int i = 0; i < PPW; ++i, t += 2) {
    // consume prefetched x -> bf16 B fragments for both tiles
    u32x4 bfA[2], bfB[2];
    bfA[0] = __builtin_bit_cast(u32x4, mk_bf8(xn[0], xn[1]));
    bfA[1] = __builtin_bit_cast(u32x4, mk_bf8(xn[2], xn[3]));
    bfB[0] = __builtin_bit_cast(u32x4, mk_bf8(xn[4], xn[5]));
    bfB[1] = __builtin_bit_cast(u32x4, mk_bf8(xn[6], xn[7]));

    // issue next pair's loads (hidden under ~2500cy of compute)
    {
      int tn = (i + 1 < PPW) ? (t + 2) : t;
      const float* p0 = x + (size_t)(tn * 16 + b) * 64 + 8 * h;
      xn[0] = *(const f32x4*)(p0);        xn[1] = *(const f32x4*)(p0 + 4);
      xn[2] = *(const f32x4*)(p0 + 32);   xn[3] = *(const f32x4*)(p0 + 36);
      const float* p1 = p0 + 1024;
      xn[4] = *(const f32x4*)(p1);        xn[5] = *(const f32x4*)(p1 + 4);
      xn[6] = *(const f32x4*)(p1 + 32);   xn[7] = *(const f32x4*)(p1 + 36);
    }

    // ---- three (Linear -> gelu -> LN) blocks, two tiles in flight ----
    #pragma unroll
    for (int L = 0; L < 3; ++L) {
      const uint8_t* wp = Wl + L * 8192 + rowB;
      f32x4 accA[4], accB[4];
      #pragma unroll
      for (int mt = 0; mt < 4; ++mt) {
        u32x4 w0 = *(const u32x4*)(wp + mt * 2048 + ((kOff     ) ^ swzW));
        u32x4 w1 = *(const u32x4*)(wp + mt * 2048 + ((kOff + 64) ^ swzW));
        f32x4 bini = *(const f32x4*)(biasL + L * 64 + 16 * mt + 4 * h);
        accA[mt] = __builtin_amdgcn_mfma_f32_16x16x32_bf16(
            __builtin_bit_cast(bf16x8, w0), __builtin_bit_cast(bf16x8, bfA[0]), bini, 0, 0, 0);
        accA[mt] = __builtin_amdgcn_mfma_f32_16x16x32_bf16(
            __builtin_bit_cast(bf16x8, w1), __builtin_bit_cast(bf16x8, bfA[1]), accA[mt], 0, 0, 0);
        accB[mt] = __builtin_amdgcn_mfma_f32_16x16x32_bf16(
            __builtin_bit_cast(bf16x8, w0), __builtin_bit_cast(bf16x8, bfB[0]), bini, 0, 0, 0);
        accB[mt] = __builtin_amdgcn_mfma_f32_16x16x32_bf16(
            __builtin_bit_cast(bf16x8, w1), __builtin_bit_cast(bf16x8, bfB[1]), accB[mt], 0, 0, 0);
      }

      #pragma unroll
      for (int mt = 0; mt < 4; ++mt) { accA[mt] = gelu4(accA[mt]); accB[mt] = gelu4(accB[mt]); }

      // LayerNorm stats (vector partial sums -> horizontal -> 2-step shfl)
      f32x4 vsA = accA[0] + accA[1] + accA[2] + accA[3];
      f32x4 vsB = accB[0] + accB[1] + accB[2] + accB[3];
      f32x4 vqA = accA[0]*accA[0] + accA[1]*accA[1] + accA[2]*accA[2] + accA[3]*accA[3];
      f32x4 vqB = accB[0]*accB[0] + accB[1]*accB[1] + accB[2]*accB[2] + accB[3]*accB[3];
      float s1A = (vsA[0]+vsA[1]) + (vsA[2]+vsA[3]);
      float s2A = (vqA[0]+vqA[1]) + (vqA[2]+vqA[3]);
      float s1B = (vsB[0]+vsB[1]) + (vsB[2]+vsB[3]);
      float s2B = (vqB[0]+vqB[1]) + (vqB[2]+vqB[3]);
      s1A += __shfl_xor(s1A, 16); s2A += __shfl_xor(s2A, 16);
      s1B += __shfl_xor(s1B, 16); s2B += __shfl_xor(s2B, 16);
      s1A += __shfl_xor(s1A, 32); s2A += __shfl_xor(s2A, 32);
      s1B += __shfl_xor(s1B, 32); s2B += __shfl_xor(s2B, 32);
      float muA = s1A * (1.0f/64.0f), muB = s1B * (1.0f/64.0f);
      float vrA = __builtin_fmaf(s2A, (1.0f/64.0f), -muA*muA);
      float vrB = __builtin_fmaf(s2B, (1.0f/64.0f), -muB*muB);
      float rsA = rsqrtf(vrA + 1e-5f), rsB = rsqrtf(vrB + 1e-5f);
      float nmA = -muA * rsA,          nmB = -muB * rsB;

      // normalize + affine -> bf16 -> swizzled LDS bounce -> next B frags
      #pragma unroll
      for (int mt = 0; mt < 4; ++mt) {
        f32x4 nA = (accA[mt] * rsA + nmA) * ggr[mt] + bbr[mt];
        f32x4 nB = (accB[mt] * rsB + nmB) * ggr[mt] + bbr[mt];
        bf16x2 a0 = { (__bf16)nA[0], (__bf16)nA[1] };
        bf16x2 a1 = { (__bf16)nA[2], (__bf16)nA[3] };
        bf16x2 c0 = { (__bf16)nB[0], (__bf16)nB[1] };
        bf16x2 c1 = { (__bf16)nB[2], (__bf16)nB[3] };
        int di = (b * 32 + 8 * mt + 2 * h) ^ swzD;
        u32x2 pa = { __builtin_bit_cast(uint32_t, a0), __builtin_bit_cast(uint32_t, a1) };
        u32x2 pc = { __builtin_bit_cast(uint32_t, c0), __builtin_bit_cast(uint32_t, c1) };
        *(u32x2*)(myA  + di) = pa;
        *(u32x2*)(myBB + di) = pc;
      }
      #pragma unroll
      for (int s = 0; s < 2; ++s) {
        int di = (b * 32 + 16 * s + 4 * h) ^ swzD;
        bfA[s] = *(const u32x4*)(myA  + di);
        bfB[s] = *(const u32x4*)(myBB + di);
      }
    }

    // ---- output projection (shared Wo frags) ----
    f32x4 aoA = aoInit, aoB = aoInit;
    {
      const uint8_t* wp = Wl + 24576 + rowB;
      u32x4 w0 = *(const u32x4*)(wp + ((kOff     ) ^ swzW));
      u32x4 w1 = *(const u32x4*)(wp + ((kOff + 64) ^ swzW));
      aoA = __builtin_amdgcn_mfma_f32_16x16x32_bf16(
          __builtin_bit_cast(bf16x8, w0), __builtin_bit_cast(bf16x8, bfA[0]), aoA, 0, 0, 0);
      aoA = __builtin_amdgcn_mfma_f32_16x16x32_bf16(
          __builtin_bit_cast(bf16x8, w1), __builtin_bit_cast(bf16x8, bfA[1]), aoA, 0, 0, 0);
      aoB = __builtin_amdgcn_mfma_f32_16x16x32_bf16(
          __builtin_bit_cast(bf16x8, w0), __builtin_bit_cast(bf16x8, bfB[0]), aoB, 0, 0, 0);
      aoB = __builtin_amdgcn_mfma_f32_16x16x32_bf16(
          __builtin_bit_cast(bf16x8, w1), __builtin_bit_cast(bf16x8, bfB[1]), aoB, 0, 0, 0);
    }

    // gather pair outputs (160 floats) in LDS, store 640B coalesced
    #pragma unroll
    for (int r = 0; r < 4; ++r) {
      int v = 4 * h + r;
      if (v < VOCAB) {
        myF[     b * VOCAB + v] = aoA[r];
        myF[80 + b * VOCAB + v] = aoB[r];
      }
    }
    float* dst = tmp + (size_t)t * 80;   // 80 floats per tile, pair contiguous
    dst[lane]       = myF[lane];
    dst[64 + lane]  = myF[64 + lane];
    if (lane < 32) dst[128 + lane] = myF[128 + lane];
  }
}

// symmetrize: out[b,i,j,:] = 0.5*(tmp[b,i,j,:] + tmp[b,j,i,:]), LDS tile transpose
__global__ __launch_bounds__(256)
void sym_kernel(const float* __restrict__ tmp, float* __restrict__ out)
{
  __shared__ float A[32][164];
  __shared__ float B[32][164];
  int bid = blockIdx.x;
  int bb = bid / 144, r2 = bid - bb * 144;
  int ti = r2 / 12,  tj = r2 - ti * 12;
  int i0 = ti * 32,  j0 = tj * 32;
  const size_t base = (size_t)bb * SDIM * SDIM;

  for (int idx = threadIdx.x; idx < 32 * 160; idx += 256) {
    int r = idx / 160, c = idx - r * 160;
    A[r][c] = tmp[(base + (size_t)(i0 + r) * SDIM + j0) * VOCAB + c];
    B[r][c] = tmp[(base + (size_t)(j0 + r) * SDIM + i0) * VOCAB + c];
  }
  __syncthreads();
  for (int idx = threadIdx.x; idx < 32 * 160; idx += 256) {
    int r = idx / 160, c = idx - r * 160;
    int jc = c / 5, v = c - jc * 5;
    out[(base + (size_t)(i0 + r) * SDIM + j0) * VOCAB + c] =
        0.5f * (A[r][c] + B[jc][r * 5 + v]);
  }
}

extern "C" void kernel_launch(void* const* d_in, const int* in_sizes, int n_in,
                              void* d_out, int out_size, void* d_ws, size_t ws_size,
                              hipStream_t stream)
{
  const float* x   = (const float*)d_in[0];
  const float* W1  = (const float*)d_in[1];
  const float* b1  = (const float*)d_in[2];
  const float* W2  = (const float*)d_in[3];
  const float* b2  = (const float*)d_in[4];
  const float* W3  = (const float*)d_in[5];
  const float* b3  = (const float*)d_in[6];
  const float* lng = (const float*)d_in[7];
  const float* lnb = (const float*)d_in[8];
  const float* Wo  = (const float*)d_in[9];
  const float* bo  = (const float*)d_in[10];

  float* tmp = (float*)d_ws;   // 23.6 MB scratch
  float* out = (float*)d_out;

  mlp_kernel<<<BLOCKS, 256, 0, stream>>>(x, W1, b1, W2, b2, W3, b3,
                                         lng, lnb, Wo, bo, tmp);
  sym_kernel<<<8 * 12 * 12, 256, 0, stream>>>(tmp, out);
}

// Round 6
// 147.728 us; speedup vs baseline: 1.4037x; 1.4037x over previous
//
#include <hip/hip_runtime.h>
#include <cstdint>
#include <cstddef>

typedef __attribute__((ext_vector_type(8))) __bf16   bf16x8;
typedef __attribute__((ext_vector_type(2))) __bf16   bf16x2;
typedef __attribute__((ext_vector_type(4))) float    f32x4;
typedef __attribute__((ext_vector_type(4))) uint32_t u32x4;

#define N_ROWS   1179648   // 8*384*384
#define N_TILES  73728     // N_ROWS/16
#define BLOCKS   2048      // 4 waves -> 8192 waves -> 9 tiles/wave
#define TPW      9
#define SDIM     384
#define VOCAB    5

// LDS map (28672 B total -> 5 blocks/CU):
#define WO_OFF   24576
#define BIAS_OFF 26624
#define OUT_OFF  27392     // 4 waves x 320B out-gather

// tanh-form GELU via exp2+rcp on f32x4: gelu(x) ~= x / (1 + exp2(x*(c1+c2*x^2)))
// |err vs exact| <= ~4e-4 (threshold is 7.75e-2)
__device__ __forceinline__ f32x4 gelu4(f32x4 x){
  f32x4 u = x * x;
  f32x4 w = u * (-0.10294456f) + (-2.3021255f);
  f32x4 z = x * w;
  f32x4 e;
  e[0] = __builtin_amdgcn_exp2f(z[0]);
  e[1] = __builtin_amdgcn_exp2f(z[1]);
  e[2] = __builtin_amdgcn_exp2f(z[2]);
  e[3] = __builtin_amdgcn_exp2f(z[3]);
  f32x4 d = e + 1.0f;
  f32x4 r;
  r[0] = __builtin_amdgcn_rcpf(d[0]);
  r[1] = __builtin_amdgcn_rcpf(d[1]);
  r[2] = __builtin_amdgcn_rcpf(d[2]);
  r[3] = __builtin_amdgcn_rcpf(d[3]);
  return x * r;
}

__device__ __forceinline__ bf16x8 mk_bf8(f32x4 a, f32x4 b){
  bf16x8 v;
  v[0]=(__bf16)a[0]; v[1]=(__bf16)a[1]; v[2]=(__bf16)a[2]; v[3]=(__bf16)a[3];
  v[4]=(__bf16)b[0]; v[5]=(__bf16)b[1]; v[6]=(__bf16)b[2]; v[7]=(__bf16)b[3];
  return v;
}

// W-row permutation: global row m -> LDS A-row rho, so that acc[mt][r] of lane
// (h,b) equals feature 8h + r + 4*(mt&1) + 32*(mt>>1). Then the next layer's
// B fragment is a pure in-register repack (no LDS bounce, no cross-lane).
__device__ __forceinline__ int perm_rho(int m){
  return (m & 0x23) | ((m & 4) << 2) | ((m & 0x18) >> 1);
}

__global__ __launch_bounds__(256)
void mlp_kernel(const float* __restrict__ x,
                const float* __restrict__ W1, const float* __restrict__ b1,
                const float* __restrict__ W2, const float* __restrict__ b2,
                const float* __restrict__ W3, const float* __restrict__ b3,
                const float* __restrict__ lng, const float* __restrict__ lnb,
                const float* __restrict__ Wo,  const float* __restrict__ bo,
                float* __restrict__ tmp)
{
  __shared__ __align__(16) uint8_t Wl[28672];

  const int tid = threadIdx.x;

  // ---- stage: W1..W3 fp32 -> LDS bf16, permuted rows, swizzle byte^=((rho&7)<<4) ----
  {
    int m = tid & 63, g = tid >> 6;
    int rho = perm_rho(m);
    uint8_t* wrow = Wl + rho * 128;
    int swz = (rho & 7) << 4;
    #pragma unroll 1
    for (int idx = g; idx < 96; idx += 4) {   // idx = L*32 + kp
      int L = idx >> 5, kp = idx & 31;
      const float* W = (L == 0) ? W1 : ((L == 1) ? W2 : W3);
      float lo = W[(2 * kp    ) * 64 + m];
      float hi = W[(2 * kp + 1) * 64 + m];
      bf16x2 p = { (__bf16)lo, (__bf16)hi };
      *(uint32_t*)(wrow + L * 8192 + ((4 * kp) ^ swz)) = __builtin_bit_cast(uint32_t, p);
    }
    int mm = tid & 15;
    #pragma unroll 1
    for (int kp = tid >> 4; kp < 32; kp += 16) {    // Wo^T rows 0..15 natural (>=5 zero)
      float lo = (mm < VOCAB) ? Wo[(2 * kp    ) * VOCAB + mm] : 0.0f;
      float hi = (mm < VOCAB) ? Wo[(2 * kp + 1) * VOCAB + mm] : 0.0f;
      bf16x2 p = { (__bf16)lo, (__bf16)hi };
      *(uint32_t*)(Wl + WO_OFF + mm * 128 + ((4 * kp) ^ ((mm & 7) << 4))) =
          __builtin_bit_cast(uint32_t, p);
    }
    if (tid < 192) {                                 // biases -> LDS f32 (natural order)
      float v = (tid < 64) ? b1[tid] : ((tid < 128) ? b2[tid - 64] : b3[tid - 128]);
      *(float*)(Wl + BIAS_OFF + tid * 4) = v;
    }
  }
  __syncthreads();

  const int wav  = tid >> 6, lane = tid & 63;
  const int h    = lane >> 4;            // k sub-block selector
  const int b    = lane & 15;            // batch-row in tile / A-row p
  const int swzW = (b & 7) << 4;
  const int rowB = b * 128;
  const int kOff = 16 * h;
  const float* biasL = (const float*)(Wl + BIAS_OFF);
  float* myF = (float*)(Wl + OUT_OFF) + wav * 80;

  // per-lane feature bases for the 4 acc sets (permuted layout)
  // base(mt) = 8h + 4*(mt&1) + 32*(mt>>1)
  f32x4 ggr[4], bbr[4], aoInit;
  #pragma unroll
  for (int mt = 0; mt < 4; ++mt) {
    int base = 8 * h + 4 * (mt & 1) + 32 * (mt >> 1);
    ggr[mt] = *(const f32x4*)(lng + base);
    bbr[mt] = *(const f32x4*)(lnb + base);
  }
  #pragma unroll
  for (int r = 0; r < 4; ++r) {
    int v = 4 * h + r;
    aoInit[r] = (v < VOCAB) ? bo[v] : 0.0f;
  }

  const int gw = blockIdx.x * 4 + wav;   // 0..8191
  int t = gw * TPW;

  // prime x prefetch (tile t): feats 8h..8h+7 and 32+8h..+7 of row b
  f32x4 xn[4];
  {
    const float* px = x + (size_t)(t * 16 + b) * 64 + 8 * h;
    xn[0] = *(const f32x4*)(px);      xn[1] = *(const f32x4*)(px + 4);
    xn[2] = *(const f32x4*)(px + 32); xn[3] = *(const f32x4*)(px + 36);
  }

  #pragma unroll 1
  for (int i = 0; i < TPW; ++i, ++t) {
    u32x4 bfr[2];
    bfr[0] = __builtin_bit_cast(u32x4, mk_bf8(xn[0], xn[1]));
    bfr[1] = __builtin_bit_cast(u32x4, mk_bf8(xn[2], xn[3]));

    { // prefetch next tile's x (hidden under this tile's compute)
      int tn = (i + 1 < TPW) ? (t + 1) : t;
      const float* pn = x + (size_t)(tn * 16 + b) * 64 + 8 * h;
      xn[0] = *(const f32x4*)(pn);      xn[1] = *(const f32x4*)(pn + 4);
      xn[2] = *(const f32x4*)(pn + 32); xn[3] = *(const f32x4*)(pn + 36);
    }

    // ---- three (Linear -> gelu -> LN) blocks, zero inter-layer LDS ----
    #pragma unroll
    for (int L = 0; L < 3; ++L) {
      const uint8_t* wp = Wl + L * 8192 + rowB;
      f32x4 acc[4];
      #pragma unroll
      for (int mt = 0; mt < 4; ++mt) {
        u32x4 w0 = *(const u32x4*)(wp + mt * 2048 + ((kOff     ) ^ swzW));
        u32x4 w1 = *(const u32x4*)(wp + mt * 2048 + ((kOff + 64) ^ swzW));
        int base = 8 * h + 4 * (mt & 1) + 32 * (mt >> 1);
        acc[mt] = *(const f32x4*)(biasL + L * 64 + base);
        acc[mt] = __builtin_amdgcn_mfma_f32_16x16x32_bf16(
            __builtin_bit_cast(bf16x8, w0), __builtin_bit_cast(bf16x8, bfr[0]), acc[mt], 0, 0, 0);
        acc[mt] = __builtin_amdgcn_mfma_f32_16x16x32_bf16(
            __builtin_bit_cast(bf16x8, w1), __builtin_bit_cast(bf16x8, bfr[1]), acc[mt], 0, 0, 0);
      }

      #pragma unroll
      for (int mt = 0; mt < 4; ++mt) acc[mt] = gelu4(acc[mt]);

      // LayerNorm stats over row b (partition across lanes b, b+16, b+32, b+48)
      f32x4 vs = acc[0] + acc[1] + acc[2] + acc[3];
      f32x4 vq = acc[0]*acc[0] + acc[1]*acc[1] + acc[2]*acc[2] + acc[3]*acc[3];
      float s1 = (vs[0]+vs[1]) + (vs[2]+vs[3]);
      float s2 = (vq[0]+vq[1]) + (vq[2]+vq[3]);
      s1 += __shfl_xor(s1, 16); s2 += __shfl_xor(s2, 16);
      s1 += __shfl_xor(s1, 32); s2 += __shfl_xor(s2, 32);
      float mu   = s1 * (1.0f/64.0f);
      float var  = __builtin_fmaf(s2, (1.0f/64.0f), -mu * mu);
      float rstd = rsqrtf(var + 1e-5f);
      float nm   = -mu * rstd;

      // normalize + affine, then PURE-REGISTER repack into next B fragments:
      // acc[0]|acc[1] -> feats 8h..8h+7 ; acc[2]|acc[3] -> feats 32+8h..+7
      f32x4 n0 = (acc[0] * rstd + nm) * ggr[0] + bbr[0];
      f32x4 n1 = (acc[1] * rstd + nm) * ggr[1] + bbr[1];
      f32x4 n2 = (acc[2] * rstd + nm) * ggr[2] + bbr[2];
      f32x4 n3 = (acc[3] * rstd + nm) * ggr[3] + bbr[3];
      bfr[0] = __builtin_bit_cast(u32x4, mk_bf8(n0, n1));
      bfr[1] = __builtin_bit_cast(u32x4, mk_bf8(n2, n3));
    }

    // ---- output projection out^T = Wo^T . h3^T + bo (natural m order) ----
    f32x4 ao = aoInit;
    {
      const uint8_t* wp = Wl + WO_OFF + rowB;
      u32x4 w0 = *(const u32x4*)(wp + ((kOff     ) ^ swzW));
      u32x4 w1 = *(const u32x4*)(wp + ((kOff + 64) ^ swzW));
      ao = __builtin_amdgcn_mfma_f32_16x16x32_bf16(
          __builtin_bit_cast(bf16x8, w0), __builtin_bit_cast(bf16x8, bfr[0]), ao, 0, 0, 0);
      ao = __builtin_amdgcn_mfma_f32_16x16x32_bf16(
          __builtin_bit_cast(bf16x8, w1), __builtin_bit_cast(bf16x8, bfr[1]), ao, 0, 0, 0);
    }

    // gather 16x5 floats in per-wave LDS slot, store 320B coalesced
    #pragma unroll
    for (int r = 0; r < 4; ++r) {
      int v = 4 * h + r;
      if (v < VOCAB) myF[b * VOCAB + v] = ao[r];
    }
    float* dst = tmp + (size_t)t * 80;
    dst[lane] = myF[lane];
    if (lane < 16) dst[64 + lane] = myF[64 + lane];
  }
}

// symmetrize: out[b,i,j,:] = 0.5*(tmp[b,i,j,:] + tmp[b,j,i,:]), LDS tile transpose
__global__ __launch_bounds__(256)
void sym_kernel(const float* __restrict__ tmp, float* __restrict__ out)
{
  __shared__ float A[32][164];
  __shared__ float B[32][164];
  int bid = blockIdx.x;
  int bb = bid / 144, r2 = bid - bb * 144;
  int ti = r2 / 12,  tj = r2 - ti * 12;
  int i0 = ti * 32,  j0 = tj * 32;
  const size_t base = (size_t)bb * SDIM * SDIM;

  for (int idx = threadIdx.x; idx < 32 * 160; idx += 256) {
    int r = idx / 160, c = idx - r * 160;
    A[r][c] = tmp[(base + (size_t)(i0 + r) * SDIM + j0) * VOCAB + c];
    B[r][c] = tmp[(base + (size_t)(j0 + r) * SDIM + i0) * VOCAB + c];
  }
  __syncthreads();
  for (int idx = threadIdx.x; idx < 32 * 160; idx += 256) {
    int r = idx / 160, c = idx - r * 160;
    int jc = c / 5, v = c - jc * 5;
    out[(base + (size_t)(i0 + r) * SDIM + j0) * VOCAB + c] =
        0.5f * (A[r][c] + B[jc][r * 5 + v]);
  }
}

extern "C" void kernel_launch(void* const* d_in, const int* in_sizes, int n_in,
                              void* d_out, int out_size, void* d_ws, size_t ws_size,
                              hipStream_t stream)
{
  const float* x   = (const float*)d_in[0];
  const float* W1  = (const float*)d_in[1];
  const float* b1  = (const float*)d_in[2];
  const float* W2  = (const float*)d_in[3];
  const float* b2  = (const float*)d_in[4];
  const float* W3  = (const float*)d_in[5];
  const float* b3  = (const float*)d_in[6];
  const float* lng = (const float*)d_in[7];
  const float* lnb = (const float*)d_in[8];
  const float* Wo  = (const float*)d_in[9];
  const float* bo  = (const float*)d_in[10];

  float* tmp = (float*)d_ws;   // 23.6 MB scratch
  float* out = (float*)d_out;

  mlp_kernel<<<BLOCKS, 256, 0, stream>>>(x, W1, b1, W2, b2, W3, b3,
                                         lng, lnb, Wo, bo, tmp);
  sym_kernel<<<8 * 12 * 12, 256, 0, stream>>>(tmp, out);
}